// Round 1
// baseline (280.719 us; speedup 1.0000x reference)
//
#include <hip/hip_runtime.h>
#include <stdint.h>

#define TOK   8192
#define DIM   1024
#define NEXP  8
#define TOPK  2

typedef unsigned short ushort_t;
typedef __attribute__((ext_vector_type(8))) short bf16x8;
typedef __attribute__((ext_vector_type(4))) float f32x4;

__device__ __forceinline__ unsigned short f2bf(float f) {
  unsigned int u = __float_as_uint(f);
  u += 0x7fffu + ((u >> 16) & 1u);
  return (unsigned short)(u >> 16);
}

__device__ __forceinline__ void gload_lds16(const void* g, void* l) {
  __builtin_amdgcn_global_load_lds(
      (const __attribute__((address_space(1))) void*)(uintptr_t)g,
      (__attribute__((address_space(3))) void*)(unsigned int)(uintptr_t)l,
      16, 0, 0);
}

// ---------------- conversion kernels ----------------
__global__ __launch_bounds__(256) void k_cast_x(const float* __restrict__ x,
                                                ushort_t* __restrict__ xb) {
  const int i = (blockIdx.x * 256 + threadIdx.x) * 8;
  const float4 a = *(const float4*)(x + i);
  const float4 b = *(const float4*)(x + i + 4);
  union { ushort_t u[8]; uint4 v; } s;
  s.u[0] = f2bf(a.x); s.u[1] = f2bf(a.y); s.u[2] = f2bf(a.z); s.u[3] = f2bf(a.w);
  s.u[4] = f2bf(b.x); s.u[5] = f2bf(b.y); s.u[6] = f2bf(b.z); s.u[7] = f2bf(b.w);
  *(uint4*)(xb + i) = s.v;
}

// Wsh1T[n][k] (interleaved): even n -> sg col n/2, odd n -> su col n/2. [1024][1024]
__global__ __launch_bounds__(256) void k_build_wsh1(const float* __restrict__ sg,
                                                    const float* __restrict__ su,
                                                    ushort_t* __restrict__ W) {
  const int idx = blockIdx.x * 256 + threadIdx.x;           // < 1024*1024
  const int n = idx >> 10, k = idx & 1023;
  const float* src = (n & 1) ? su : sg;
  W[idx] = f2bf(src[k * 512 + (n >> 1)]);
}
// WsdT[n][k] = sd[k][n]. [1024][512]
__global__ __launch_bounds__(256) void k_build_wsd(const float* __restrict__ sd,
                                                   ushort_t* __restrict__ W) {
  const int idx = blockIdx.x * 256 + threadIdx.x;           // < 1024*512
  const int n = idx >> 9, k = idx & 511;
  W[idx] = f2bf(sd[k * 1024 + n]);
}
// WguT[e][n][k]: even n -> w_gate[e] col n/2, odd -> w_up. [8][512][1024]
__global__ __launch_bounds__(256) void k_build_wgu(const float* __restrict__ wg,
                                                   const float* __restrict__ wu,
                                                   ushort_t* __restrict__ W) {
  const int idx = blockIdx.x * 256 + threadIdx.x;           // < 8*512*1024
  const int e = idx >> 19;
  const int r = idx & ((1 << 19) - 1);
  const int n = r >> 10, k = r & 1023;
  const float* src = (n & 1) ? wu : wg;
  W[idx] = f2bf(src[((size_t)e * 1024 + k) * 256 + (n >> 1)]);
}
// WdT[e][n][k] = w_down[e][k][n]. [8][1024][256]
__global__ __launch_bounds__(256) void k_build_wd(const float* __restrict__ wd,
                                                  ushort_t* __restrict__ W) {
  const int idx = blockIdx.x * 256 + threadIdx.x;           // < 8*1024*256
  const int e = idx >> 18;
  const int r = idx & ((1 << 18) - 1);
  const int n = r >> 8, k = r & 255;
  W[idx] = f2bf(wd[((size_t)e * 256 + k) * 1024 + n]);
}

// ---------------- router (fp32, matches reference selection) ----------------
__global__ __launch_bounds__(256) void k_router(const float* __restrict__ x,
                                                const float* __restrict__ Wg,
                                                int* __restrict__ tid,
                                                float* __restrict__ tw) {
  __shared__ float sWg[DIM * NEXP];
  for (int i = threadIdx.x; i < DIM * NEXP; i += 256) sWg[i] = Wg[i];
  __syncthreads();
  const int wid = threadIdx.x >> 6, lane = threadIdx.x & 63;
  const int t = blockIdx.x * 4 + wid;
  float acc[NEXP];
#pragma unroll
  for (int e = 0; e < NEXP; ++e) acc[e] = 0.f;
  const float* xr = x + (size_t)t * DIM;
  for (int i = lane; i < DIM; i += 64) {
    const float xv = xr[i];
#pragma unroll
    for (int e = 0; e < NEXP; ++e) acc[e] += xv * sWg[i * NEXP + e];
  }
#pragma unroll
  for (int e = 0; e < NEXP; ++e) {
    float v = acc[e];
#pragma unroll
    for (int o = 32; o > 0; o >>= 1) v += __shfl_xor(v, o);
    acc[e] = v;
  }
  if (lane == 0) {
    float mx = acc[0];
#pragma unroll
    for (int e = 1; e < NEXP; ++e) mx = fmaxf(mx, acc[e]);
    float p[NEXP]; float s = 0.f;
#pragma unroll
    for (int e = 0; e < NEXP; ++e) { p[e] = __expf(acc[e] - mx); s += p[e]; }
    const float inv = 1.f / s;
#pragma unroll
    for (int e = 0; e < NEXP; ++e) p[e] *= inv;
    int i1 = 0; float s1 = p[0];
#pragma unroll
    for (int e = 1; e < NEXP; ++e) if (p[e] > s1) { s1 = p[e]; i1 = e; }
    int i2 = -1; float s2 = -1.f;
#pragma unroll
    for (int e = 0; e < NEXP; ++e) if (e != i1 && p[e] > s2) { s2 = p[e]; i2 = e; }
    tid[t * 2] = i1; tid[t * 2 + 1] = i2;
    tw[t * 2] = s1;  tw[t * 2 + 1] = s2;
  }
}

// ---------------- histogram + prefix ----------------
__global__ __launch_bounds__(256) void k_scan(const int* __restrict__ tid,
                                              int* __restrict__ cnt,
                                              int* __restrict__ off,
                                              int* __restrict__ cnt2) {
  __shared__ int h[NEXP];
  if (threadIdx.x < NEXP) h[threadIdx.x] = 0;
  __syncthreads();
  int loc[NEXP];
#pragma unroll
  for (int e = 0; e < NEXP; ++e) loc[e] = 0;
  for (int i = threadIdx.x; i < TOK * TOPK; i += 256) {
    const int v = tid[i];
#pragma unroll
    for (int e = 0; e < NEXP; ++e) loc[e] += (v == e);
  }
#pragma unroll
  for (int e = 0; e < NEXP; ++e) if (loc[e]) atomicAdd(&h[e], loc[e]);
  __syncthreads();
  if (threadIdx.x == 0) {
    int run = 0;
    for (int e = 0; e < NEXP; ++e) { off[e] = run; cnt[e] = h[e]; run += h[e]; }
  }
  if (threadIdx.x < NEXP) cnt2[threadIdx.x] = 0;
}

// ---------------- ballot-ranked scatter ----------------
__global__ __launch_bounds__(256) void k_scatter(const int* __restrict__ tid,
                                                 const float* __restrict__ tw,
                                                 const int* __restrict__ off,
                                                 int* __restrict__ cnt2,
                                                 int* __restrict__ tok,
                                                 float* __restrict__ wgt) {
  const int t = blockIdx.x * 256 + threadIdx.x;
  const int lane = threadIdx.x & 63;
#pragma unroll
  for (int j = 0; j < TOPK; ++j) {
    const int e = tid[t * 2 + j];
    const float w = tw[t * 2 + j];
    int slot = 0;
#pragma unroll
    for (int ee = 0; ee < NEXP; ++ee) {
      const unsigned long long m = __ballot(e == ee);
      if (m) {
        const int r = __popcll(m & ((1ull << lane) - 1ull));
        const int leader = __ffsll((unsigned long long)m) - 1;
        int base = 0;
        if (lane == leader) base = atomicAdd(&cnt2[ee], (int)__popcll(m));
        base = __shfl(base, leader);
        if (e == ee) slot = off[ee] + base + r;
      }
    }
    tok[slot] = t;
    wgt[slot] = w;
  }
}

// ---------------- templated MFMA GEMM ----------------
// A [M][K] bf16 (optionally gathered rows), B [NC][K] bf16 (B^T layout).
// MODE 0: SwiGLU fuse (interleaved gate/up cols) -> bf16 hOut [.][NC/2]
// MODE 1: plain fp32 store to fOut [M][NC]
// MODE 2: scale by wgt[row], atomicAdd into fOut[tok[row]][*]
template <int K, int NC, int MODE, bool GATHER>
__global__ __launch_bounds__(256) void k_gemm(
    const ushort_t* __restrict__ A, const ushort_t* __restrict__ B,
    ushort_t* __restrict__ hOut, float* __restrict__ fOut,
    const int* __restrict__ tok, const float* __restrict__ wgt,
    const int* __restrict__ cnt, const int* __restrict__ off, int M) {
  __shared__ __attribute__((aligned(16))) ushort_t lA[128 * 64];
  __shared__ __attribute__((aligned(16))) ushort_t lB[128 * 64];
  const int e = blockIdx.z;
  const int m_e = (MODE == 2 || GATHER) ? cnt[e] : M;
  const int mBase = blockIdx.y * 128;
  if (mBase >= m_e) return;
  const int nBase = blockIdx.x * 128;
  const int offE = (MODE == 2 || GATHER) ? off[e] : 0;
  const ushort_t* Bblk = B + (size_t)e * NC * K;
  const ushort_t* Ablk = (MODE == 2) ? (A + (size_t)offE * K) : A;

  const int wid = threadIdx.x >> 6, lane = threadIdx.x & 63;
  const int wm = wid >> 1, wn = wid & 1;
  const int l15 = lane & 15, lq = lane >> 4;

  // staging geometry: chunk c covers LDS rows 8c..8c+7; lane -> (row, 16B slot)
  const ushort_t* aptr[4];
  const ushort_t* bptr[4];
#pragma unroll
  for (int cc = 0; cc < 4; ++cc) {
    const int c = wid * 4 + cc;
    const int rl = c * 8 + (lane >> 3);              // 0..127 tile row
    const int slot = (lane & 7) ^ (rl & 7);          // swizzled logical 16B slot
    const int g = mBase + rl;
    const int gc = (g < m_e) ? g : (m_e - 1);
    const ushort_t* ar;
    if (GATHER) ar = A + (size_t)tok[offE + gc] * K;
    else        ar = Ablk + (size_t)gc * K;
    aptr[cc] = ar + slot * 8;
    bptr[cc] = Bblk + (size_t)(nBase + rl) * K + slot * 8;
  }

  f32x4 acc[4][4];
#pragma unroll
  for (int mi = 0; mi < 4; ++mi)
#pragma unroll
    for (int ni = 0; ni < 4; ++ni) acc[mi][ni] = (f32x4){0.f, 0.f, 0.f, 0.f};

  for (int kt = 0; kt < K; kt += 64) {
#pragma unroll
    for (int cc = 0; cc < 4; ++cc) {
      const int c = wid * 4 + cc;
      gload_lds16(aptr[cc] + kt, &lA[c * 512]);
      gload_lds16(bptr[cc] + kt, &lB[c * 512]);
    }
    __syncthreads();
#pragma unroll
    for (int kk = 0; kk < 2; ++kk) {
      bf16x8 af[4], bfr[4];
#pragma unroll
      for (int mi = 0; mi < 4; ++mi) {
        const int row = wm * 64 + mi * 16 + l15;
        const int cb = ((kk * 32 + lq * 8) * 2) ^ ((row & 7) << 4);
        af[mi] = *(const bf16x8*)((const char*)lA + row * 128 + cb);
      }
#pragma unroll
      for (int ni = 0; ni < 4; ++ni) {
        const int row = wn * 64 + ni * 16 + l15;
        const int cb = ((kk * 32 + lq * 8) * 2) ^ ((row & 7) << 4);
        bfr[ni] = *(const bf16x8*)((const char*)lB + row * 128 + cb);
      }
#pragma unroll
      for (int mi = 0; mi < 4; ++mi)
#pragma unroll
        for (int ni = 0; ni < 4; ++ni)
          acc[mi][ni] = __builtin_amdgcn_mfma_f32_16x16x32_bf16(
              af[mi], bfr[ni], acc[mi][ni], 0, 0, 0);
    }
    __syncthreads();
  }

  // epilogue
#pragma unroll
  for (int mi = 0; mi < 4; ++mi) {
#pragma unroll
    for (int r = 0; r < 4; ++r) {
      const int g = mBase + wm * 64 + mi * 16 + lq * 4 + r;
      int tk = 0; float w = 0.f;
      if (MODE == 2) {
        if (g < m_e) { tk = tok[offE + g]; w = wgt[offE + g]; }
      }
#pragma unroll
      for (int ni = 0; ni < 4; ++ni) {
        const float v = acc[mi][ni][r];
        const int c = nBase + wn * 64 + ni * 16 + l15;
        if (MODE == 0) {
          const float o = __shfl_xor(v, 1);   // partner column (gate<->up)
          if (!(c & 1) && g < m_e) {
            const float hv = (v / (1.f + __expf(-v))) * o;  // silu(gate)*up
            const int orow = GATHER ? (offE + g) : g;
            hOut[(size_t)orow * (NC / 2) + (c >> 1)] = f2bf(hv);
          }
        } else if (MODE == 1) {
          fOut[(size_t)g * NC + c] = v;
        } else {
          if (g < m_e) atomicAdd(&fOut[(size_t)tk * NC + c], v * w);
        }
      }
    }
  }
}

// ---------------- launch ----------------
extern "C" void kernel_launch(void* const* d_in, const int* in_sizes, int n_in,
                              void* d_out, int out_size, void* d_ws, size_t ws_size,
                              hipStream_t stream) {
  (void)in_sizes; (void)n_in; (void)out_size; (void)ws_size;
  const float* x      = (const float*)d_in[0];
  const float* Wg     = (const float*)d_in[1];
  const float* w_gate = (const float*)d_in[2];
  const float* w_up   = (const float*)d_in[3];
  const float* w_down = (const float*)d_in[4];
  const float* sg     = (const float*)d_in[5];
  const float* su     = (const float*)d_in[6];
  const float* sd     = (const float*)d_in[7];
  float* out = (float*)d_out;

  char* ws = (char*)d_ws;
  size_t o = 0;
  ushort_t* xb   = (ushort_t*)(ws + o); o += (size_t)TOK * DIM * 2;
  ushort_t* Wsh1 = (ushort_t*)(ws + o); o += (size_t)1024 * 1024 * 2;
  ushort_t* Wsd  = (ushort_t*)(ws + o); o += (size_t)1024 * 512 * 2;
  ushort_t* Wgu  = (ushort_t*)(ws + o); o += (size_t)NEXP * 512 * 1024 * 2;
  ushort_t* Wd   = (ushort_t*)(ws + o); o += (size_t)NEXP * 1024 * 256 * 2;
  ushort_t* hs   = (ushort_t*)(ws + o); o += (size_t)TOK * 512 * 2;
  ushort_t* he   = (ushort_t*)(ws + o); o += (size_t)TOK * TOPK * 256 * 2;
  int*   tid  = (int*)(ws + o);   o += (size_t)TOK * TOPK * 4;
  float* tw   = (float*)(ws + o); o += (size_t)TOK * TOPK * 4;
  int*   tok  = (int*)(ws + o);   o += (size_t)TOK * TOPK * 4;
  float* wgt  = (float*)(ws + o); o += (size_t)TOK * TOPK * 4;
  int*   cnt  = (int*)(ws + o);   o += 64;
  int*   offp = (int*)(ws + o);   o += 64;
  int*   cnt2 = (int*)(ws + o);   o += 64;

  k_cast_x<<<TOK * DIM / 8 / 256, 256, 0, stream>>>(x, xb);
  k_build_wsh1<<<1024 * 1024 / 256, 256, 0, stream>>>(sg, su, Wsh1);
  k_build_wsd<<<1024 * 512 / 256, 256, 0, stream>>>(sd, Wsd);
  k_build_wgu<<<NEXP * 512 * 1024 / 256, 256, 0, stream>>>(w_gate, w_up, Wgu);
  k_build_wd<<<NEXP * 1024 * 256 / 256, 256, 0, stream>>>(w_down, Wd);
  k_router<<<TOK / 4, 256, 0, stream>>>(x, Wg, tid, tw);
  k_scan<<<1, 256, 0, stream>>>(tid, cnt, offp, cnt2);
  k_scatter<<<TOK / 256, 256, 0, stream>>>(tid, tw, offp, cnt2, tok, wgt);

  // shared expert GEMM1: xb[8192,1024] x Wsh1[1024,1024]^T -> hs[8192,512] (SwiGLU)
  k_gemm<1024, 1024, 0, false><<<dim3(8, 64, 1), 256, 0, stream>>>(
      xb, Wsh1, hs, nullptr, nullptr, nullptr, nullptr, nullptr, TOK);
  // routed GEMM1 (gathered): xb rows via tok -> he[slot,256] (SwiGLU)
  k_gemm<1024, 512, 0, true><<<dim3(4, 64, NEXP), 256, 0, stream>>>(
      xb, Wgu, he, nullptr, tok, wgt, cnt, offp, TOK);
  // shared expert GEMM2: hs[8192,512] x Wsd[1024,512]^T -> out (plain fp32 store)
  k_gemm<512, 1024, 1, false><<<dim3(8, 64, 1), 256, 0, stream>>>(
      hs, Wsd, nullptr, out, nullptr, nullptr, nullptr, nullptr, TOK);
  // routed GEMM2: he[slot,256] x Wd[e][1024,256]^T, scale by wgt, atomicAdd to out
  k_gemm<256, 1024, 2, false><<<dim3(8, 64, NEXP), 256, 0, stream>>>(
      he, Wd, nullptr, out, tok, wgt, cnt, offp, TOK);
}

// Round 2
// 229.941 us; speedup vs baseline: 1.2208x; 1.2208x over previous
//
#include <hip/hip_runtime.h>
#include <stdint.h>

#define TOK   8192
#define DIM   1024
#define NEXP  8
#define TOPK  2

typedef unsigned short ushort_t;
typedef __attribute__((ext_vector_type(8))) short bf16x8;
typedef __attribute__((ext_vector_type(4))) float f32x4;

__device__ __forceinline__ unsigned short f2bf(float f) {
  unsigned int u = __float_as_uint(f);
  u += 0x7fffu + ((u >> 16) & 1u);
  return (unsigned short)(u >> 16);
}
__device__ __forceinline__ float bf2f(ushort_t u) {
  return __uint_as_float(((unsigned int)u) << 16);
}

__device__ __forceinline__ void gload_lds16(const void* g, void* l) {
  __builtin_amdgcn_global_load_lds(
      (const __attribute__((address_space(1))) void*)(uintptr_t)g,
      (__attribute__((address_space(3))) void*)(unsigned int)(uintptr_t)l,
      16, 0, 0);
}

// ---------------- x cast ----------------
__global__ __launch_bounds__(256) void k_cast_x(const float* __restrict__ x,
                                                ushort_t* __restrict__ xb) {
  const int i = (blockIdx.x * 256 + threadIdx.x) * 8;
  const float4 a = *(const float4*)(x + i);
  const float4 b = *(const float4*)(x + i + 4);
  union { ushort_t u[8]; uint4 v; } s;
  s.u[0] = f2bf(a.x); s.u[1] = f2bf(a.y); s.u[2] = f2bf(a.z); s.u[3] = f2bf(a.w);
  s.u[4] = f2bf(b.x); s.u[5] = f2bf(b.y); s.u[6] = f2bf(b.z); s.u[7] = f2bf(b.w);
  *(uint4*)(xb + i) = s.v;
}

// ---------------- fused coalesced weight transpose (one dispatch) ----------------
// Tiles of 64x64, LDS-staged, both sides coalesced. Segments:
//  [0,128)   Wsh1: sg/su [1024][512]  -> [1024][1024] interleaved
//  [128,256) Wsd : sd    [512][1024]  -> [1024][512]
//  [256,768) Wgu : w_gate/w_up [e][1024][256] -> [e][512][1024] interleaved
//  [768,1280)Wd  : w_down[e][256][1024] -> [e][1024][256]
__global__ __launch_bounds__(256) void k_transpose_all(
    const float* __restrict__ sg, const float* __restrict__ su,
    const float* __restrict__ sd, const float* __restrict__ wg,
    const float* __restrict__ wu, const float* __restrict__ wdn,
    ushort_t* __restrict__ Wsh1, ushort_t* __restrict__ Wsd,
    ushort_t* __restrict__ Wgu, ushort_t* __restrict__ Wd) {
  __shared__ float t[64][65];
  int b = blockIdx.x;
  const float *s0, *s1 = nullptr; ushort_t* dst; int R, C; bool ilv;
  int r0, c0;
  if (b < 128) {
    ilv = true; s0 = sg; s1 = su; dst = Wsh1; R = 1024; C = 512;
    c0 = (b & 7) * 64; r0 = (b >> 3) * 64;
  } else if (b < 256) {
    b -= 128; ilv = false; s0 = sd; dst = Wsd; R = 512; C = 1024;
    c0 = (b & 15) * 64; r0 = (b >> 4) * 64;
  } else if (b < 768) {
    b -= 256; const int e = b >> 6; b &= 63;
    ilv = true;
    s0 = wg + (size_t)e * 1024 * 256; s1 = wu + (size_t)e * 1024 * 256;
    dst = Wgu + (size_t)e * 512 * 1024; R = 1024; C = 256;
    c0 = (b & 3) * 64; r0 = (b >> 2) * 64;
  } else {
    b -= 768; const int e = b >> 6; b &= 63;
    ilv = false;
    s0 = wdn + (size_t)e * 256 * 1024;
    dst = Wd + (size_t)e * 1024 * 256; R = 256; C = 1024;
    c0 = (b & 15) * 64; r0 = (b >> 4) * 64;
  }
  const int tx = threadIdx.x & 63, ty = threadIdx.x >> 6;
  const int np = ilv ? 2 : 1;
  for (int p = 0; p < np; ++p) {
    const float* s = p ? s1 : s0;
    __syncthreads();
#pragma unroll
    for (int i = 0; i < 64; i += 4)
      t[ty + i][tx] = s[(size_t)(r0 + ty + i) * C + c0 + tx];
    __syncthreads();
#pragma unroll
    for (int i = 0; i < 64; i += 4) {
      const int n = c0 + ty + i;
      const int drow = ilv ? (2 * n + p) : n;
      dst[(size_t)drow * R + r0 + tx] = f2bf(t[tx][ty + i]);
    }
  }
}

// ---------------- router (fp32, matches reference selection) ----------------
__global__ __launch_bounds__(256) void k_router(const float* __restrict__ x,
                                                const float* __restrict__ Wg,
                                                int* __restrict__ tid,
                                                float* __restrict__ tw) {
  __shared__ float sWgT[NEXP * DIM];   // [e][i] — conflict-free inner reads
  for (int j = threadIdx.x; j < DIM * NEXP; j += 256)
    sWgT[(j & 7) * DIM + (j >> 3)] = Wg[j];
  __syncthreads();
  const int wid = threadIdx.x >> 6, lane = threadIdx.x & 63;
  const int t = blockIdx.x * 4 + wid;
  float acc[NEXP];
#pragma unroll
  for (int e = 0; e < NEXP; ++e) acc[e] = 0.f;
  const float* xr = x + (size_t)t * DIM;
  for (int i = lane; i < DIM; i += 64) {
    const float xv = xr[i];
#pragma unroll
    for (int e = 0; e < NEXP; ++e) acc[e] += xv * sWgT[e * DIM + i];
  }
#pragma unroll
  for (int e = 0; e < NEXP; ++e) {
    float v = acc[e];
#pragma unroll
    for (int o = 32; o > 0; o >>= 1) v += __shfl_xor(v, o);
    acc[e] = v;
  }
  if (lane == 0) {
    float mx = acc[0];
#pragma unroll
    for (int e = 1; e < NEXP; ++e) mx = fmaxf(mx, acc[e]);
    float p[NEXP]; float s = 0.f;
#pragma unroll
    for (int e = 0; e < NEXP; ++e) { p[e] = __expf(acc[e] - mx); s += p[e]; }
    const float inv = 1.f / s;
#pragma unroll
    for (int e = 0; e < NEXP; ++e) p[e] *= inv;
    int i1 = 0; float s1 = p[0];
#pragma unroll
    for (int e = 1; e < NEXP; ++e) if (p[e] > s1) { s1 = p[e]; i1 = e; }
    int i2 = -1; float s2 = -1.f;
#pragma unroll
    for (int e = 0; e < NEXP; ++e) if (e != i1 && p[e] > s2) { s2 = p[e]; i2 = e; }
    tid[t * 2] = i1; tid[t * 2 + 1] = i2;
    tw[t * 2] = s1;  tw[t * 2 + 1] = s2;
  }
}

// ---------------- histogram + prefix ----------------
__global__ __launch_bounds__(256) void k_scan(const int* __restrict__ tid,
                                              int* __restrict__ cnt,
                                              int* __restrict__ off,
                                              int* __restrict__ cnt2) {
  __shared__ int h[NEXP];
  if (threadIdx.x < NEXP) h[threadIdx.x] = 0;
  __syncthreads();
  int loc[NEXP];
#pragma unroll
  for (int e = 0; e < NEXP; ++e) loc[e] = 0;
  for (int i = threadIdx.x; i < TOK * TOPK; i += 256) {
    const int v = tid[i];
#pragma unroll
    for (int e = 0; e < NEXP; ++e) loc[e] += (v == e);
  }
#pragma unroll
  for (int e = 0; e < NEXP; ++e) if (loc[e]) atomicAdd(&h[e], loc[e]);
  __syncthreads();
  if (threadIdx.x == 0) {
    int run = 0;
    for (int e = 0; e < NEXP; ++e) { off[e] = run; cnt[e] = h[e]; run += h[e]; }
  }
  if (threadIdx.x < NEXP) cnt2[threadIdx.x] = 0;
}

// ---------------- ballot-ranked scatter (+ inverse map slotof) ----------------
__global__ __launch_bounds__(256) void k_scatter(const int* __restrict__ tid,
                                                 const float* __restrict__ tw,
                                                 const int* __restrict__ off,
                                                 int* __restrict__ cnt2,
                                                 int* __restrict__ tok,
                                                 float* __restrict__ wgt,
                                                 int* __restrict__ slotof) {
  const int t = blockIdx.x * 256 + threadIdx.x;
  const int lane = threadIdx.x & 63;
#pragma unroll
  for (int j = 0; j < TOPK; ++j) {
    const int e = tid[t * 2 + j];
    const float w = tw[t * 2 + j];
    int slot = 0;
#pragma unroll
    for (int ee = 0; ee < NEXP; ++ee) {
      const unsigned long long m = __ballot(e == ee);
      if (m) {
        const int r = __popcll(m & ((1ull << lane) - 1ull));
        const int leader = __ffsll((unsigned long long)m) - 1;
        int base = 0;
        if (lane == leader) base = atomicAdd(&cnt2[ee], (int)__popcll(m));
        base = __shfl(base, leader);
        if (e == ee) slot = off[ee] + base + r;
      }
    }
    tok[slot] = t;
    wgt[slot] = w;
    slotof[t * 2 + j] = slot;
  }
}

// ---------------- templated MFMA GEMM ----------------
// A [M][K] bf16, B [NC][K] bf16 (B^T). Per-expert when PERE.
// MODE 0: SwiGLU fuse (interleaved cols) -> bf16 hOut [.][NC/2]
// MODE 1: scaled bf16 contrib store: hOut[(offE+g)*NC+c] = bf(v*wgt)
// MODE 2: combine: fOut[g*NC+c] = v + cIn[slot1] + cIn[slot2]  (slots via tok)
// MODE 3: plain fp32 store (fallback)
// MODE 4: scaled fp32 atomicAdd into fOut[tok[row]] (fallback)
template <int K, int NC, int MODE, bool GATHER>
__global__ __launch_bounds__(256) void k_gemm(
    const ushort_t* __restrict__ A, const ushort_t* __restrict__ B,
    ushort_t* __restrict__ hOut, float* __restrict__ fOut,
    const ushort_t* __restrict__ cIn,
    const int* __restrict__ tok, const float* __restrict__ wgt,
    const int* __restrict__ cnt, const int* __restrict__ off, int M) {
  constexpr bool PERE = GATHER || (MODE == 1) || (MODE == 4);
  __shared__ __attribute__((aligned(16))) ushort_t lA[128 * 64];
  __shared__ __attribute__((aligned(16))) ushort_t lB[128 * 64];
  const int e = blockIdx.z;
  const int m_e = PERE ? cnt[e] : M;
  const int mBase = blockIdx.y * 128;
  if (mBase >= m_e) return;
  const int nBase = blockIdx.x * 128;
  const int offE = PERE ? off[e] : 0;
  const ushort_t* Bblk = B + (size_t)e * NC * K;
  const ushort_t* Ablk = ((MODE == 1) || (MODE == 4)) ? (A + (size_t)offE * K) : A;

  const int wid = threadIdx.x >> 6, lane = threadIdx.x & 63;
  const int wm = wid >> 1, wn = wid & 1;
  const int l15 = lane & 15, lq = lane >> 4;

  const ushort_t* aptr[4];
  const ushort_t* bptr[4];
#pragma unroll
  for (int cc = 0; cc < 4; ++cc) {
    const int c = wid * 4 + cc;
    const int rl = c * 8 + (lane >> 3);
    const int slot = (lane & 7) ^ (rl & 7);
    const int g = mBase + rl;
    const int gc = (g < m_e) ? g : (m_e - 1);
    const ushort_t* ar;
    if (GATHER) ar = A + (size_t)tok[offE + gc] * K;
    else        ar = Ablk + (size_t)gc * K;
    aptr[cc] = ar + slot * 8;
    bptr[cc] = Bblk + (size_t)(nBase + rl) * K + slot * 8;
  }

  f32x4 acc[4][4];
#pragma unroll
  for (int mi = 0; mi < 4; ++mi)
#pragma unroll
    for (int ni = 0; ni < 4; ++ni) acc[mi][ni] = (f32x4){0.f, 0.f, 0.f, 0.f};

  for (int kt = 0; kt < K; kt += 64) {
#pragma unroll
    for (int cc = 0; cc < 4; ++cc) {
      const int c = wid * 4 + cc;
      gload_lds16(aptr[cc] + kt, &lA[c * 512]);
      gload_lds16(bptr[cc] + kt, &lB[c * 512]);
    }
    __syncthreads();
#pragma unroll
    for (int kk = 0; kk < 2; ++kk) {
      bf16x8 af[4], bfr[4];
#pragma unroll
      for (int mi = 0; mi < 4; ++mi) {
        const int row = wm * 64 + mi * 16 + l15;
        const int cb = ((kk * 32 + lq * 8) * 2) ^ ((row & 7) << 4);
        af[mi] = *(const bf16x8*)((const char*)lA + row * 128 + cb);
      }
#pragma unroll
      for (int ni = 0; ni < 4; ++ni) {
        const int row = wn * 64 + ni * 16 + l15;
        const int cb = ((kk * 32 + lq * 8) * 2) ^ ((row & 7) << 4);
        bfr[ni] = *(const bf16x8*)((const char*)lB + row * 128 + cb);
      }
#pragma unroll
      for (int mi = 0; mi < 4; ++mi)
#pragma unroll
        for (int ni = 0; ni < 4; ++ni)
          acc[mi][ni] = __builtin_amdgcn_mfma_f32_16x16x32_bf16(
              af[mi], bfr[ni], acc[mi][ni], 0, 0, 0);
    }
    __syncthreads();
  }

#pragma unroll
  for (int mi = 0; mi < 4; ++mi) {
#pragma unroll
    for (int r = 0; r < 4; ++r) {
      const int g = mBase + wm * 64 + mi * 16 + lq * 4 + r;
      int tk = 0; float w = 0.f; int sl1 = 0, sl2 = 0;
      if (MODE == 1 || MODE == 4) {
        if (g < m_e) { w = wgt[offE + g]; if (MODE == 4) tk = tok[offE + g]; }
      }
      if (MODE == 2) { sl1 = tok[g * 2]; sl2 = tok[g * 2 + 1]; }
#pragma unroll
      for (int ni = 0; ni < 4; ++ni) {
        const float v = acc[mi][ni][r];
        const int c = nBase + wn * 64 + ni * 16 + l15;
        if (MODE == 0) {
          const float o = __shfl_xor(v, 1);
          if (!(c & 1) && g < m_e) {
            const float hv = (v / (1.f + __expf(-v))) * o;
            const int orow = GATHER ? (offE + g) : g;
            hOut[(size_t)orow * (NC / 2) + (c >> 1)] = f2bf(hv);
          }
        } else if (MODE == 1) {
          if (g < m_e) hOut[(size_t)(offE + g) * NC + c] = f2bf(v * w);
        } else if (MODE == 2) {
          fOut[(size_t)g * NC + c] =
              v + bf2f(cIn[(size_t)sl1 * NC + c]) + bf2f(cIn[(size_t)sl2 * NC + c]);
        } else if (MODE == 3) {
          fOut[(size_t)g * NC + c] = v;
        } else {
          if (g < m_e) atomicAdd(&fOut[(size_t)tk * NC + c], v * w);
        }
      }
    }
  }
}

// ---------------- launch ----------------
extern "C" void kernel_launch(void* const* d_in, const int* in_sizes, int n_in,
                              void* d_out, int out_size, void* d_ws, size_t ws_size,
                              hipStream_t stream) {
  (void)in_sizes; (void)n_in; (void)out_size;
  const float* x      = (const float*)d_in[0];
  const float* Wg     = (const float*)d_in[1];
  const float* w_gate = (const float*)d_in[2];
  const float* w_up   = (const float*)d_in[3];
  const float* w_down = (const float*)d_in[4];
  const float* sg     = (const float*)d_in[5];
  const float* su     = (const float*)d_in[6];
  const float* sd     = (const float*)d_in[7];
  float* out = (float*)d_out;

  char* ws = (char*)d_ws;
  size_t o = 0;
  ushort_t* xb    = (ushort_t*)(ws + o); o += (size_t)TOK * DIM * 2;
  ushort_t* Wsh1  = (ushort_t*)(ws + o); o += (size_t)1024 * 1024 * 2;
  ushort_t* Wsd   = (ushort_t*)(ws + o); o += (size_t)1024 * 512 * 2;
  ushort_t* Wgu   = (ushort_t*)(ws + o); o += (size_t)NEXP * 512 * 1024 * 2;
  ushort_t* Wd    = (ushort_t*)(ws + o); o += (size_t)NEXP * 1024 * 256 * 2;
  ushort_t* hs    = (ushort_t*)(ws + o); o += (size_t)TOK * 512 * 2;
  ushort_t* he    = (ushort_t*)(ws + o); o += (size_t)TOK * TOPK * 256 * 2;
  int*   tid   = (int*)(ws + o);   o += (size_t)TOK * TOPK * 4;
  float* tw    = (float*)(ws + o); o += (size_t)TOK * TOPK * 4;
  int*   tok   = (int*)(ws + o);   o += (size_t)TOK * TOPK * 4;
  float* wgt   = (float*)(ws + o); o += (size_t)TOK * TOPK * 4;
  int*   slotof= (int*)(ws + o);   o += (size_t)TOK * TOPK * 4;
  int*   cnt   = (int*)(ws + o);   o += 64;
  int*   offp  = (int*)(ws + o);   o += 64;
  int*   cnt2  = (int*)(ws + o);   o += 64;
  ushort_t* contrib = (ushort_t*)(ws + o);
  const size_t need = o + (size_t)TOK * TOPK * DIM * 2;
  const bool bigws = ws_size >= need;

  k_cast_x<<<TOK * DIM / 8 / 256, 256, 0, stream>>>(x, xb);
  k_transpose_all<<<1280, 256, 0, stream>>>(sg, su, sd, w_gate, w_up, w_down,
                                            Wsh1, Wsd, Wgu, Wd);
  k_router<<<TOK / 4, 256, 0, stream>>>(x, Wg, tid, tw);
  k_scan<<<1, 256, 0, stream>>>(tid, cnt, offp, cnt2);
  k_scatter<<<TOK / 256, 256, 0, stream>>>(tid, tw, offp, cnt2, tok, wgt, slotof);

  // shared GEMM1: xb x Wsh1^T -> hs [8192,512] (SwiGLU)
  k_gemm<1024, 1024, 0, false><<<dim3(8, 64, 1), 256, 0, stream>>>(
      xb, Wsh1, hs, nullptr, nullptr, nullptr, nullptr, nullptr, nullptr, TOK);
  // routed GEMM1 (gathered): xb rows via tok -> he [slot,256] (SwiGLU)
  k_gemm<1024, 512, 0, true><<<dim3(4, 64, NEXP), 256, 0, stream>>>(
      xb, Wgu, he, nullptr, nullptr, tok, wgt, cnt, offp, TOK);

  if (bigws) {
    // routed GEMM2: he x Wd^T, scale by wgt -> bf16 contrib[slot,1024]
    k_gemm<256, 1024, 1, false><<<dim3(8, 64, NEXP), 256, 0, stream>>>(
        he, Wd, contrib, nullptr, nullptr, tok, wgt, cnt, offp, TOK);
    // shared GEMM2 + combine: hs x Wsd^T + contrib[slot1]+contrib[slot2] -> out
    k_gemm<512, 1024, 2, false><<<dim3(8, 64, 1), 256, 0, stream>>>(
        hs, Wsd, nullptr, out, contrib, slotof, nullptr, nullptr, nullptr, TOK);
  } else {
    // fallback: plain store then atomics
    k_gemm<512, 1024, 3, false><<<dim3(8, 64, 1), 256, 0, stream>>>(
        hs, Wsd, nullptr, out, nullptr, nullptr, nullptr, nullptr, nullptr, TOK);
    k_gemm<256, 1024, 4, false><<<dim3(8, 64, NEXP), 256, 0, stream>>>(
        he, Wd, nullptr, out, nullptr, tok, wgt, cnt, offp, TOK);
  }
}

// Round 4
// 224.603 us; speedup vs baseline: 1.2498x; 1.0238x over previous
//
#include <hip/hip_runtime.h>
#include <stdint.h>

#define TOK   8192
#define DIM   1024
#define NEXP  8
#define TOPK  2

typedef unsigned short ushort_t;
typedef __attribute__((ext_vector_type(8))) short bf16x8;
typedef __attribute__((ext_vector_type(4))) float f32x4;

__device__ __forceinline__ unsigned short f2bf(float f) {
  unsigned int u = __float_as_uint(f);
  u += 0x7fffu + ((u >> 16) & 1u);
  return (unsigned short)(u >> 16);
}
__device__ __forceinline__ float bf2f(ushort_t u) {
  return __uint_as_float(((unsigned int)u) << 16);
}

__device__ __forceinline__ void gload_lds16(const void* g, void* l) {
  __builtin_amdgcn_global_load_lds(
      (const __attribute__((address_space(1))) void*)(uintptr_t)g,
      (__attribute__((address_space(3))) void*)(unsigned int)(uintptr_t)l,
      16, 0, 0);
}

// ---------------- x cast ----------------
__global__ __launch_bounds__(256) void k_cast_x(const float* __restrict__ x,
                                                ushort_t* __restrict__ xb) {
  const int i = (blockIdx.x * 256 + threadIdx.x) * 8;
  const float4 a = *(const float4*)(x + i);
  const float4 b = *(const float4*)(x + i + 4);
  union { ushort_t u[8]; uint4 v; } s;
  s.u[0] = f2bf(a.x); s.u[1] = f2bf(a.y); s.u[2] = f2bf(a.z); s.u[3] = f2bf(a.w);
  s.u[4] = f2bf(b.x); s.u[5] = f2bf(b.y); s.u[6] = f2bf(b.z); s.u[7] = f2bf(b.w);
  *(uint4*)(xb + i) = s.v;
}

// ---------------- fused coalesced weight transpose ----------------
__global__ __launch_bounds__(256) void k_transpose_all(
    const float* __restrict__ sg, const float* __restrict__ su,
    const float* __restrict__ sd, const float* __restrict__ wg,
    const float* __restrict__ wu, const float* __restrict__ wdn,
    ushort_t* __restrict__ Wsh1, ushort_t* __restrict__ Wsd,
    ushort_t* __restrict__ Wgu, ushort_t* __restrict__ Wd) {
  __shared__ float t[64][65];
  int b = blockIdx.x;
  const float *s0, *s1 = nullptr; ushort_t* dst; int R, C; bool ilv;
  int r0, c0;
  if (b < 128) {
    ilv = true; s0 = sg; s1 = su; dst = Wsh1; R = 1024; C = 512;
    c0 = (b & 7) * 64; r0 = (b >> 3) * 64;
  } else if (b < 256) {
    b -= 128; ilv = false; s0 = sd; dst = Wsd; R = 512; C = 1024;
    c0 = (b & 15) * 64; r0 = (b >> 4) * 64;
  } else if (b < 768) {
    b -= 256; const int e = b >> 6; b &= 63;
    ilv = true;
    s0 = wg + (size_t)e * 1024 * 256; s1 = wu + (size_t)e * 1024 * 256;
    dst = Wgu + (size_t)e * 512 * 1024; R = 1024; C = 256;
    c0 = (b & 3) * 64; r0 = (b >> 2) * 64;
  } else {
    b -= 768; const int e = b >> 6; b &= 63;
    ilv = false;
    s0 = wdn + (size_t)e * 256 * 1024;
    dst = Wd + (size_t)e * 1024 * 256; R = 256; C = 1024;
    c0 = (b & 15) * 64; r0 = (b >> 4) * 64;
  }
  const int tx = threadIdx.x & 63, ty = threadIdx.x >> 6;
  const int np = ilv ? 2 : 1;
  for (int p = 0; p < np; ++p) {
    const float* s = p ? s1 : s0;
    __syncthreads();
#pragma unroll
    for (int i = 0; i < 64; i += 4)
      t[ty + i][tx] = s[(size_t)(r0 + ty + i) * C + c0 + tx];
    __syncthreads();
#pragma unroll
    for (int i = 0; i < 64; i += 4) {
      const int n = c0 + ty + i;
      const int drow = ilv ? (2 * n + p) : n;
      dst[(size_t)drow * R + r0 + tx] = f2bf(t[tx][ty + i]);
    }
  }
}

// ---------------- router (fp32, matches reference selection) ----------------
__global__ __launch_bounds__(256) void k_router(const float* __restrict__ x,
                                                const float* __restrict__ Wg,
                                                int* __restrict__ tid,
                                                float* __restrict__ tw) {
  __shared__ float sWgT[NEXP * DIM];
  for (int j = threadIdx.x; j < DIM * NEXP; j += 256)
    sWgT[(j & 7) * DIM + (j >> 3)] = Wg[j];
  __syncthreads();
  const int wid = threadIdx.x >> 6, lane = threadIdx.x & 63;
  const int t = blockIdx.x * 4 + wid;
  float acc[NEXP];
#pragma unroll
  for (int e = 0; e < NEXP; ++e) acc[e] = 0.f;
  const float* xr = x + (size_t)t * DIM;
  for (int i = lane; i < DIM; i += 64) {
    const float xv = xr[i];
#pragma unroll
    for (int e = 0; e < NEXP; ++e) acc[e] += xv * sWgT[e * DIM + i];
  }
#pragma unroll
  for (int e = 0; e < NEXP; ++e) {
    float v = acc[e];
#pragma unroll
    for (int o = 32; o > 0; o >>= 1) v += __shfl_xor(v, o);
    acc[e] = v;
  }
  if (lane == 0) {
    float mx = acc[0];
#pragma unroll
    for (int e = 1; e < NEXP; ++e) mx = fmaxf(mx, acc[e]);
    float p[NEXP]; float s = 0.f;
#pragma unroll
    for (int e = 0; e < NEXP; ++e) { p[e] = __expf(acc[e] - mx); s += p[e]; }
    const float inv = 1.f / s;
#pragma unroll
    for (int e = 0; e < NEXP; ++e) p[e] *= inv;
    int i1 = 0; float s1 = p[0];
#pragma unroll
    for (int e = 1; e < NEXP; ++e) if (p[e] > s1) { s1 = p[e]; i1 = e; }
    int i2 = -1; float s2 = -1.f;
#pragma unroll
    for (int e = 0; e < NEXP; ++e) if (e != i1 && p[e] > s2) { s2 = p[e]; i2 = e; }
    tid[t * 2] = i1; tid[t * 2 + 1] = i2;
    tw[t * 2] = s1;  tw[t * 2 + 1] = s2;
  }
}

// ---------------- histogram + prefix ----------------
__global__ __launch_bounds__(256) void k_scan(const int* __restrict__ tid,
                                              int* __restrict__ cnt,
                                              int* __restrict__ off,
                                              int* __restrict__ cnt2) {
  __shared__ int h[NEXP];
  if (threadIdx.x < NEXP) h[threadIdx.x] = 0;
  __syncthreads();
  int loc[NEXP];
#pragma unroll
  for (int e = 0; e < NEXP; ++e) loc[e] = 0;
  for (int i = threadIdx.x; i < TOK * TOPK; i += 256) {
    const int v = tid[i];
#pragma unroll
    for (int e = 0; e < NEXP; ++e) loc[e] += (v == e);
  }
#pragma unroll
  for (int e = 0; e < NEXP; ++e) if (loc[e]) atomicAdd(&h[e], loc[e]);
  __syncthreads();
  if (threadIdx.x == 0) {
    int run = 0;
    for (int e = 0; e < NEXP; ++e) { off[e] = run; cnt[e] = h[e]; run += h[e]; }
  }
  if (threadIdx.x < NEXP) cnt2[threadIdx.x] = 0;
}

// ---------------- ballot-ranked scatter (+ inverse map slotof) ----------------
__global__ __launch_bounds__(256) void k_scatter(const int* __restrict__ tid,
                                                 const float* __restrict__ tw,
                                                 const int* __restrict__ off,
                                                 int* __restrict__ cnt2,
                                                 int* __restrict__ tok,
                                                 float* __restrict__ wgt,
                                                 int* __restrict__ slotof) {
  const int t = blockIdx.x * 256 + threadIdx.x;
  const int lane = threadIdx.x & 63;
#pragma unroll
  for (int j = 0; j < TOPK; ++j) {
    const int e = tid[t * 2 + j];
    const float w = tw[t * 2 + j];
    int slot = 0;
#pragma unroll
    for (int ee = 0; ee < NEXP; ++ee) {
      const unsigned long long m = __ballot(e == ee);
      if (m) {
        const int r = __popcll(m & ((1ull << lane) - 1ull));
        const int leader = __ffsll((unsigned long long)m) - 1;
        int base = 0;
        if (lane == leader) base = atomicAdd(&cnt2[ee], (int)__popcll(m));
        base = __shfl(base, leader);
        if (e == ee) slot = off[ee] + base + r;
      }
    }
    tok[slot] = t;
    wgt[slot] = w;
    slotof[t * 2 + j] = slot;
  }
}

// ---------------- 1D-grid MFMA GEMM, XCD-chunked, stride-loop over m ----------------
// MODE 0: merged GEMM1. 16 groups: g<8 routed expert (gather xb rows via tok,
//         B=Wgu[g], SwiGLU -> he); g in [8,16) shared quarter/half (A=xb
//         quarter, B=Wsh1 half, SwiGLU -> hs). NC=512, K=1024.
// MODE 1: routed GEMM2. 8 groups (experts). A=he slice, B=Wd[e]. NC=1024,
//         K=256. Stores bf16 contrib[(offE+g)*1024+c] = v*wgt.
// MODE 2: shared GEMM2 + combine. 1 group. A=hs, B=Wsd. NC=1024, K=512.
//         out = v + contrib[sl1] + contrib[sl2].
template <int K, int NC, int MODE>
__global__ __launch_bounds__(256) void k_gemm1d(
    const ushort_t* __restrict__ A0, const ushort_t* __restrict__ Bgu,
    const ushort_t* __restrict__ Bsh,
    ushort_t* __restrict__ he, ushort_t* __restrict__ hs,
    ushort_t* __restrict__ contrib, float* __restrict__ out,
    const int* __restrict__ tok, const float* __restrict__ wgt,
    const int* __restrict__ cnt, const int* __restrict__ off,
    const int* __restrict__ slotof) {
  constexpr int NB = NC / 128;
  constexpr int NGROUP = (MODE == 0) ? 16 : (MODE == 1 ? 8 : 1);
  constexpr int MBSLOT = (MODE == 2) ? 64 : 16;
  constexpr int NWG = NGROUP * MBSLOT * NB;
  __shared__ __attribute__((aligned(16))) ushort_t lA[128 * 64];
  __shared__ __attribute__((aligned(16))) ushort_t lB[128 * 64];

  // XCD-chunked decode: consecutive logical wg share A-tile (nb innermost),
  // each XCD gets a contiguous chunk of logical blocks.
  const int wg = (blockIdx.x % 8) * (NWG / 8) + blockIdx.x / 8;
  const int g = wg / (MBSLOT * NB);
  const int rem = wg % (MBSLOT * NB);
  const int mbslot = rem / NB;
  const int nb = rem % NB;
  const int nBase = nb * 128;

  int m_e, offE = 0, rowq = 0, hh = 0;
  bool gat = false;
  const ushort_t* Abase = A0;
  const ushort_t* Bblk;
  if (MODE == 0) {
    if (g < 8) {
      gat = true; m_e = cnt[g]; offE = off[g];
      Bblk = Bgu + (size_t)g * 512 * 1024;
    } else {
      const int q = (g - 8) >> 1; hh = (g - 8) & 1;
      rowq = q * 2048; m_e = 2048;
      Abase = A0 + (size_t)rowq * 1024;
      Bblk = Bsh + (size_t)hh * 512 * 1024;
    }
  } else if (MODE == 1) {
    m_e = cnt[g]; offE = off[g];
    Abase = A0 + (size_t)offE * K;
    Bblk = Bgu + (size_t)g * NC * K;
  } else {
    m_e = TOK;
    Bblk = Bgu;
  }

  const int wid = threadIdx.x >> 6, lane = threadIdx.x & 63;
  const int wm = wid >> 1, wn = wid & 1;
  const int l15 = lane & 15, lq = lane >> 4;

  const ushort_t* bptr[4];
#pragma unroll
  for (int cc = 0; cc < 4; ++cc) {
    const int c = wid * 4 + cc;
    const int rl = c * 8 + (lane >> 3);
    const int slot = (lane & 7) ^ (rl & 7);
    bptr[cc] = Bblk + (size_t)(nBase + rl) * K + slot * 8;
  }

  for (int mb = mbslot; mb * 128 < m_e; mb += MBSLOT) {
    const int mBase = mb * 128;
    const ushort_t* aptr[4];
#pragma unroll
    for (int cc = 0; cc < 4; ++cc) {
      const int c = wid * 4 + cc;
      const int rl = c * 8 + (lane >> 3);
      const int slot = (lane & 7) ^ (rl & 7);
      const int gr = mBase + rl;
      const int gc = (gr < m_e) ? gr : (m_e - 1);
      const ushort_t* ar;
      if (MODE == 0 && gat) ar = A0 + (size_t)tok[offE + gc] * 1024;
      else                  ar = Abase + (size_t)gc * K;
      aptr[cc] = ar + slot * 8;
    }

    f32x4 acc[4][4];
#pragma unroll
    for (int mi = 0; mi < 4; ++mi)
#pragma unroll
      for (int ni = 0; ni < 4; ++ni) acc[mi][ni] = (f32x4){0.f, 0.f, 0.f, 0.f};

    for (int kt = 0; kt < K; kt += 64) {
#pragma unroll
      for (int cc = 0; cc < 4; ++cc) {
        const int c = wid * 4 + cc;
        gload_lds16(aptr[cc] + kt, &lA[c * 512]);
        gload_lds16(bptr[cc] + kt, &lB[c * 512]);
      }
      __syncthreads();
#pragma unroll
      for (int kk = 0; kk < 2; ++kk) {
        bf16x8 af[4], bfr[4];
#pragma unroll
        for (int mi = 0; mi < 4; ++mi) {
          const int row = wm * 64 + mi * 16 + l15;
          const int cb = ((kk * 32 + lq * 8) * 2) ^ ((row & 7) << 4);
          af[mi] = *(const bf16x8*)((const char*)lA + row * 128 + cb);
        }
#pragma unroll
        for (int ni = 0; ni < 4; ++ni) {
          const int row = wn * 64 + ni * 16 + l15;
          const int cb = ((kk * 32 + lq * 8) * 2) ^ ((row & 7) << 4);
          bfr[ni] = *(const bf16x8*)((const char*)lB + row * 128 + cb);
        }
#pragma unroll
        for (int mi = 0; mi < 4; ++mi)
#pragma unroll
          for (int ni = 0; ni < 4; ++ni)
            acc[mi][ni] = __builtin_amdgcn_mfma_f32_16x16x32_bf16(
                af[mi], bfr[ni], acc[mi][ni], 0, 0, 0);
      }
      __syncthreads();
    }

#pragma unroll
    for (int mi = 0; mi < 4; ++mi) {
#pragma unroll
      for (int r = 0; r < 4; ++r) {
        const int gg = mBase + wm * 64 + mi * 16 + lq * 4 + r;
        const bool ok = gg < m_e;
        float w = 0.f; int sl1 = 0, sl2 = 0;
        if (MODE == 1) { if (ok) w = wgt[offE + gg]; }
        if (MODE == 2) { sl1 = slotof[gg * 2]; sl2 = slotof[gg * 2 + 1]; }
#pragma unroll
        for (int ni = 0; ni < 4; ++ni) {
          const float v = acc[mi][ni][r];
          const int c = nBase + wn * 64 + ni * 16 + l15;
          if (MODE == 0) {
            const float o = __shfl_xor(v, 1);
            if (!(c & 1) && ok) {
              const float hv = (v / (1.f + __expf(-v))) * o;
              if (gat) he[(size_t)(offE + gg) * 256 + (c >> 1)] = f2bf(hv);
              else     hs[(size_t)(rowq + gg) * 512 + hh * 256 + (c >> 1)] = f2bf(hv);
            }
          } else if (MODE == 1) {
            if (ok) contrib[(size_t)(offE + gg) * 1024 + c] = f2bf(v * w);
          } else {
            out[(size_t)gg * 1024 + c] = v
                + bf2f(contrib[(size_t)sl1 * 1024 + c])
                + bf2f(contrib[(size_t)sl2 * 1024 + c]);
          }
        }
      }
    }
  }
}

// ---------------- launch ----------------
extern "C" void kernel_launch(void* const* d_in, const int* in_sizes, int n_in,
                              void* d_out, int out_size, void* d_ws, size_t ws_size,
                              hipStream_t stream) {
  (void)in_sizes; (void)n_in; (void)out_size; (void)ws_size;
  const float* x      = (const float*)d_in[0];
  const float* Wg     = (const float*)d_in[1];
  const float* w_gate = (const float*)d_in[2];
  const float* w_up   = (const float*)d_in[3];
  const float* w_down = (const float*)d_in[4];
  const float* sg     = (const float*)d_in[5];
  const float* su     = (const float*)d_in[6];
  const float* sd     = (const float*)d_in[7];
  float* out = (float*)d_out;

  char* ws = (char*)d_ws;
  size_t o = 0;
  ushort_t* xb    = (ushort_t*)(ws + o); o += (size_t)TOK * DIM * 2;
  ushort_t* Wsh1  = (ushort_t*)(ws + o); o += (size_t)1024 * 1024 * 2;
  ushort_t* Wsd   = (ushort_t*)(ws + o); o += (size_t)1024 * 512 * 2;
  ushort_t* Wgu   = (ushort_t*)(ws + o); o += (size_t)NEXP * 512 * 1024 * 2;
  ushort_t* Wd    = (ushort_t*)(ws + o); o += (size_t)NEXP * 1024 * 256 * 2;
  ushort_t* hs    = (ushort_t*)(ws + o); o += (size_t)TOK * 512 * 2;
  ushort_t* he    = (ushort_t*)(ws + o); o += (size_t)TOK * TOPK * 256 * 2;
  int*   tid   = (int*)(ws + o);   o += (size_t)TOK * TOPK * 4;
  float* tw    = (float*)(ws + o); o += (size_t)TOK * TOPK * 4;
  int*   tok   = (int*)(ws + o);   o += (size_t)TOK * TOPK * 4;
  float* wgt   = (float*)(ws + o); o += (size_t)TOK * TOPK * 4;
  int*   slotof= (int*)(ws + o);   o += (size_t)TOK * TOPK * 4;
  int*   cnt   = (int*)(ws + o);   o += 64;
  int*   offp  = (int*)(ws + o);   o += 64;
  int*   cnt2  = (int*)(ws + o);   o += 64;
  ushort_t* contrib = (ushort_t*)(ws + o);  // TOK*TOPK*DIM bf16 (33.5 MB)

  k_cast_x<<<TOK * DIM / 8 / 256, 256, 0, stream>>>(x, xb);
  k_transpose_all<<<1280, 256, 0, stream>>>(sg, su, sd, w_gate, w_up, w_down,
                                            Wsh1, Wsd, Wgu, Wd);
  k_router<<<TOK / 4, 256, 0, stream>>>(x, Wg, tid, tw);
  k_scan<<<1, 256, 0, stream>>>(tid, cnt, offp, cnt2);
  k_scatter<<<TOK / 256, 256, 0, stream>>>(tid, tw, offp, cnt2, tok, wgt, slotof);

  // merged GEMM1 (routed gathered + shared), 16*16*4 = 1024 blocks
  k_gemm1d<1024, 512, 0><<<1024, 256, 0, stream>>>(
      xb, Wgu, Wsh1, he, hs, nullptr, nullptr, tok, wgt, cnt, offp, nullptr);
  // routed GEMM2 -> bf16 contrib, 8*16*8 = 1024 blocks
  k_gemm1d<256, 1024, 1><<<1024, 256, 0, stream>>>(
      he, Wd, nullptr, nullptr, nullptr, contrib, nullptr, tok, wgt, cnt, offp,
      nullptr);
  // shared GEMM2 + combine -> out, 1*64*8 = 512 blocks
  k_gemm1d<512, 1024, 2><<<512, 256, 0, stream>>>(
      hs, Wsd, nullptr, nullptr, nullptr, contrib, out, tok, wgt, cnt, offp,
      slotof);
}

// Round 5
// 201.611 us; speedup vs baseline: 1.3924x; 1.1140x over previous
//
#include <hip/hip_runtime.h>
#include <stdint.h>

#define TOK   8192
#define DIM   1024
#define NEXP  8
#define TOPK  2

typedef unsigned short ushort_t;
typedef __attribute__((ext_vector_type(8))) short bf16x8;
typedef __attribute__((ext_vector_type(4))) float f32x4;

__device__ __forceinline__ unsigned short f2bf(float f) {
  unsigned int u = __float_as_uint(f);
  u += 0x7fffu + ((u >> 16) & 1u);
  return (unsigned short)(u >> 16);
}
__device__ __forceinline__ float bf2f(ushort_t u) {
  return __uint_as_float(((unsigned int)u) << 16);
}

__device__ __forceinline__ void gload_lds16(const void* g, void* l) {
  __builtin_amdgcn_global_load_lds(
      (const __attribute__((address_space(1))) void*)(uintptr_t)g,
      (__attribute__((address_space(3))) void*)(unsigned int)(uintptr_t)l,
      16, 0, 0);
}

// ---------------- fused coalesced weight transpose ----------------
__global__ __launch_bounds__(256) void k_transpose_all(
    const float* __restrict__ sg, const float* __restrict__ su,
    const float* __restrict__ sd, const float* __restrict__ wg,
    const float* __restrict__ wu, const float* __restrict__ wdn,
    ushort_t* __restrict__ Wsh1, ushort_t* __restrict__ Wsd,
    ushort_t* __restrict__ Wgu, ushort_t* __restrict__ Wd) {
  __shared__ float t[64][65];
  int b = blockIdx.x;
  const float *s0, *s1 = nullptr; ushort_t* dst; int R, C; bool ilv;
  int r0, c0;
  if (b < 128) {
    ilv = true; s0 = sg; s1 = su; dst = Wsh1; R = 1024; C = 512;
    c0 = (b & 7) * 64; r0 = (b >> 3) * 64;
  } else if (b < 256) {
    b -= 128; ilv = false; s0 = sd; dst = Wsd; R = 512; C = 1024;
    c0 = (b & 15) * 64; r0 = (b >> 4) * 64;
  } else if (b < 768) {
    b -= 256; const int e = b >> 6; b &= 63;
    ilv = true;
    s0 = wg + (size_t)e * 1024 * 256; s1 = wu + (size_t)e * 1024 * 256;
    dst = Wgu + (size_t)e * 512 * 1024; R = 1024; C = 256;
    c0 = (b & 3) * 64; r0 = (b >> 2) * 64;
  } else {
    b -= 768; const int e = b >> 6; b &= 63;
    ilv = false;
    s0 = wdn + (size_t)e * 256 * 1024;
    dst = Wd + (size_t)e * 1024 * 256; R = 256; C = 1024;
    c0 = (b & 15) * 64; r0 = (b >> 4) * 64;
  }
  const int tx = threadIdx.x & 63, ty = threadIdx.x >> 6;
  const int np = ilv ? 2 : 1;
  for (int p = 0; p < np; ++p) {
    const float* s = p ? s1 : s0;
    __syncthreads();
#pragma unroll
    for (int i = 0; i < 64; i += 4)
      t[ty + i][tx] = s[(size_t)(r0 + ty + i) * C + c0 + tx];
    __syncthreads();
#pragma unroll
    for (int i = 0; i < 64; i += 4) {
      const int n = c0 + ty + i;
      const int drow = ilv ? (2 * n + p) : n;
      dst[(size_t)drow * R + r0 + tx] = f2bf(t[tx][ty + i]);
    }
  }
}

// ---------------- router + x cast fused (fp32 selection path) ----------------
__global__ __launch_bounds__(256) void k_router_cast(const float* __restrict__ x,
                                                     const float* __restrict__ Wg,
                                                     ushort_t* __restrict__ xb,
                                                     int* __restrict__ tid,
                                                     float* __restrict__ tw) {
  __shared__ float sWgT[NEXP * DIM];
  for (int j = threadIdx.x; j < DIM * NEXP; j += 256)
    sWgT[(j & 7) * DIM + (j >> 3)] = Wg[j];
  __syncthreads();
  const int wid = threadIdx.x >> 6, lane = threadIdx.x & 63;
  const int t = blockIdx.x * 4 + wid;
  float acc[NEXP];
#pragma unroll
  for (int e = 0; e < NEXP; ++e) acc[e] = 0.f;
  const float* xr = x + (size_t)t * DIM;
  ushort_t* xw = xb + (size_t)t * DIM;
  for (int i = lane; i < DIM; i += 64) {
    const float xv = xr[i];
    xw[i] = f2bf(xv);
#pragma unroll
    for (int e = 0; e < NEXP; ++e) acc[e] += xv * sWgT[e * DIM + i];
  }
#pragma unroll
  for (int e = 0; e < NEXP; ++e) {
    float v = acc[e];
#pragma unroll
    for (int o = 32; o > 0; o >>= 1) v += __shfl_xor(v, o);
    acc[e] = v;
  }
  if (lane == 0) {
    float mx = acc[0];
#pragma unroll
    for (int e = 1; e < NEXP; ++e) mx = fmaxf(mx, acc[e]);
    float p[NEXP]; float s = 0.f;
#pragma unroll
    for (int e = 0; e < NEXP; ++e) { p[e] = __expf(acc[e] - mx); s += p[e]; }
    const float inv = 1.f / s;
#pragma unroll
    for (int e = 0; e < NEXP; ++e) p[e] *= inv;
    int i1 = 0; float s1 = p[0];
#pragma unroll
    for (int e = 1; e < NEXP; ++e) if (p[e] > s1) { s1 = p[e]; i1 = e; }
    int i2 = -1; float s2 = -1.f;
#pragma unroll
    for (int e = 0; e < NEXP; ++e) if (e != i1 && p[e] > s2) { s2 = p[e]; i2 = e; }
    tid[t * 2] = i1; tid[t * 2 + 1] = i2;
    tw[t * 2] = s1;  tw[t * 2 + 1] = s2;
  }
}

// ---------------- histogram + prefix ----------------
__global__ __launch_bounds__(256) void k_scan(const int* __restrict__ tid,
                                              int* __restrict__ cnt,
                                              int* __restrict__ off,
                                              int* __restrict__ cnt2) {
  __shared__ int h[NEXP];
  if (threadIdx.x < NEXP) h[threadIdx.x] = 0;
  __syncthreads();
  int loc[NEXP];
#pragma unroll
  for (int e = 0; e < NEXP; ++e) loc[e] = 0;
  for (int i = threadIdx.x; i < TOK * TOPK; i += 256) {
    const int v = tid[i];
#pragma unroll
    for (int e = 0; e < NEXP; ++e) loc[e] += (v == e);
  }
#pragma unroll
  for (int e = 0; e < NEXP; ++e) if (loc[e]) atomicAdd(&h[e], loc[e]);
  __syncthreads();
  if (threadIdx.x == 0) {
    int run = 0;
    for (int e = 0; e < NEXP; ++e) { off[e] = run; cnt[e] = h[e]; run += h[e]; }
  }
  if (threadIdx.x < NEXP) cnt2[threadIdx.x] = 0;
}

// ---------------- ballot-ranked scatter (+ inverse map slotof) ----------------
__global__ __launch_bounds__(256) void k_scatter(const int* __restrict__ tid,
                                                 const float* __restrict__ tw,
                                                 const int* __restrict__ off,
                                                 int* __restrict__ cnt2,
                                                 int* __restrict__ tok,
                                                 float* __restrict__ wgt,
                                                 int* __restrict__ slotof) {
  const int t = blockIdx.x * 256 + threadIdx.x;
  const int lane = threadIdx.x & 63;
#pragma unroll
  for (int j = 0; j < TOPK; ++j) {
    const int e = tid[t * 2 + j];
    const float w = tw[t * 2 + j];
    int slot = 0;
#pragma unroll
    for (int ee = 0; ee < NEXP; ++ee) {
      const unsigned long long m = __ballot(e == ee);
      if (m) {
        const int r = __popcll(m & ((1ull << lane) - 1ull));
        const int leader = __ffsll((unsigned long long)m) - 1;
        int base = 0;
        if (lane == leader) base = atomicAdd(&cnt2[ee], (int)__popcll(m));
        base = __shfl(base, leader);
        if (e == ee) slot = off[ee] + base + r;
      }
    }
    tok[slot] = t;
    wgt[slot] = w;
    slotof[t * 2 + j] = slot;
  }
}

// ---------------- 1D-grid MFMA GEMM, XCD-chunked, LDS dbuf + counted vmcnt ----
// MODE 0: merged GEMM1. 16 groups: g<8 routed expert (gather xb via tok,
//         B=Wgu[g], SwiGLU -> he); g in [8,16) shared quarter/half. K=1024.
// MODE 1: routed GEMM2. 8 expert groups. K=256. contrib = bf16(v*wgt).
// MODE 2: shared GEMM2 + combine. K=512. out = v + contrib[sl1] + contrib[sl2].
template <int K, int NC, int MODE>
__global__ __launch_bounds__(256) void k_gemm1d(
    const ushort_t* __restrict__ A0, const ushort_t* __restrict__ Bgu,
    const ushort_t* __restrict__ Bsh,
    ushort_t* __restrict__ he, ushort_t* __restrict__ hs,
    ushort_t* __restrict__ contrib, float* __restrict__ out,
    const int* __restrict__ tok, const float* __restrict__ wgt,
    const int* __restrict__ cnt, const int* __restrict__ off,
    const int* __restrict__ slotof) {
  constexpr int NB = NC / 128;
  constexpr int NGROUP = (MODE == 0) ? 16 : (MODE == 1 ? 8 : 1);
  constexpr int MBSLOT = (MODE == 2) ? 64 : 16;
  constexpr int NWG = NGROUP * MBSLOT * NB;
  __shared__ __attribute__((aligned(16))) ushort_t lA[2][128 * 64];
  __shared__ __attribute__((aligned(16))) ushort_t lB[2][128 * 64];

  const int wg = (blockIdx.x % 8) * (NWG / 8) + blockIdx.x / 8;
  const int g = wg / (MBSLOT * NB);
  const int rem = wg % (MBSLOT * NB);
  const int mbslot = rem / NB;
  const int nb = rem % NB;
  const int nBase = nb * 128;

  int m_e, offE = 0, rowq = 0, hh = 0;
  bool gat = false;
  const ushort_t* Abase = A0;
  const ushort_t* Bblk;
  if (MODE == 0) {
    if (g < 8) {
      gat = true; m_e = cnt[g]; offE = off[g];
      Bblk = Bgu + (size_t)g * 512 * 1024;
    } else {
      const int q = (g - 8) >> 1; hh = (g - 8) & 1;
      rowq = q * 2048; m_e = 2048;
      Abase = A0 + (size_t)rowq * 1024;
      Bblk = Bsh + (size_t)hh * 512 * 1024;
    }
  } else if (MODE == 1) {
    m_e = cnt[g]; offE = off[g];
    Abase = A0 + (size_t)offE * K;
    Bblk = Bgu + (size_t)g * NC * K;
  } else {
    m_e = TOK;
    Bblk = Bgu;
  }

  const int wid = threadIdx.x >> 6, lane = threadIdx.x & 63;
  const int wm = wid >> 1, wn = wid & 1;
  const int l15 = lane & 15, lq = lane >> 4;

  const ushort_t* bptr[4];
#pragma unroll
  for (int cc = 0; cc < 4; ++cc) {
    const int c = wid * 4 + cc;
    const int rl = c * 8 + (lane >> 3);
    const int slot = (lane & 7) ^ (rl & 7);
    bptr[cc] = Bblk + (size_t)(nBase + rl) * K + slot * 8;
  }

  for (int mb = mbslot; mb * 128 < m_e; mb += MBSLOT) {
    const int mBase = mb * 128;
    const ushort_t* aptr[4];
#pragma unroll
    for (int cc = 0; cc < 4; ++cc) {
      const int c = wid * 4 + cc;
      const int rl = c * 8 + (lane >> 3);
      const int slot = (lane & 7) ^ (rl & 7);
      const int gr = mBase + rl;
      const int gc = (gr < m_e) ? gr : (m_e - 1);
      const ushort_t* ar;
      if (MODE == 0 && gat) ar = A0 + (size_t)tok[offE + gc] * 1024;
      else                  ar = Abase + (size_t)gc * K;
      aptr[cc] = ar + slot * 8;
    }

    auto stage = [&](int buf, int ktv) {
#pragma unroll
      for (int cc = 0; cc < 4; ++cc) {
        const int c = wid * 4 + cc;
        gload_lds16(aptr[cc] + ktv, &lA[buf][c * 512]);
        gload_lds16(bptr[cc] + ktv, &lB[buf][c * 512]);
      }
    };

    f32x4 acc[4][4];
#pragma unroll
    for (int mi = 0; mi < 4; ++mi)
#pragma unroll
      for (int ni = 0; ni < 4; ++ni) acc[mi][ni] = (f32x4){0.f, 0.f, 0.f, 0.f};

    stage(0, 0);
    int cur = 0;
    for (int kt = 0; kt < K; kt += 64) {
      if (kt + 64 < K) {
        stage(cur ^ 1, kt + 64);          // next tile in flight across barrier
        asm volatile("s_waitcnt vmcnt(8)" ::: "memory");  // current tile done
      } else {
        asm volatile("s_waitcnt vmcnt(0)" ::: "memory");  // final drain
      }
      __builtin_amdgcn_s_barrier();
#pragma unroll
      for (int kk = 0; kk < 2; ++kk) {
        bf16x8 af[4], bfr[4];
#pragma unroll
        for (int mi = 0; mi < 4; ++mi) {
          const int row = wm * 64 + mi * 16 + l15;
          const int cb = ((kk * 32 + lq * 8) * 2) ^ ((row & 7) << 4);
          af[mi] = *(const bf16x8*)((const char*)lA + cur * 16384 + row * 128 + cb);
        }
#pragma unroll
        for (int ni = 0; ni < 4; ++ni) {
          const int row = wn * 64 + ni * 16 + l15;
          const int cb = ((kk * 32 + lq * 8) * 2) ^ ((row & 7) << 4);
          bfr[ni] = *(const bf16x8*)((const char*)lB + cur * 16384 + row * 128 + cb);
        }
#pragma unroll
        for (int mi = 0; mi < 4; ++mi)
#pragma unroll
          for (int ni = 0; ni < 4; ++ni)
            acc[mi][ni] = __builtin_amdgcn_mfma_f32_16x16x32_bf16(
                af[mi], bfr[ni], acc[mi][ni], 0, 0, 0);
      }
      __builtin_amdgcn_s_barrier();       // protect buf being restaged next iter
      cur ^= 1;
    }

#pragma unroll
    for (int mi = 0; mi < 4; ++mi) {
#pragma unroll
      for (int r = 0; r < 4; ++r) {
        const int gg = mBase + wm * 64 + mi * 16 + lq * 4 + r;
        const bool ok = gg < m_e;
        float w = 0.f; int sl1 = 0, sl2 = 0;
        if (MODE == 1) { if (ok) w = wgt[offE + gg]; }
        if (MODE == 2) { sl1 = slotof[gg * 2]; sl2 = slotof[gg * 2 + 1]; }
#pragma unroll
        for (int ni = 0; ni < 4; ++ni) {
          const float v = acc[mi][ni][r];
          const int c = nBase + wn * 64 + ni * 16 + l15;
          if (MODE == 0) {
            const float o = __shfl_xor(v, 1);
            if (!(c & 1) && ok) {
              const float hv = (v / (1.f + __expf(-v))) * o;
              if (gat) he[(size_t)(offE + gg) * 256 + (c >> 1)] = f2bf(hv);
              else     hs[(size_t)(rowq + gg) * 512 + hh * 256 + (c >> 1)] = f2bf(hv);
            }
          } else if (MODE == 1) {
            if (ok) contrib[(size_t)(offE + gg) * 1024 + c] = f2bf(v * w);
          } else {
            out[(size_t)gg * 1024 + c] = v
                + bf2f(contrib[(size_t)sl1 * 1024 + c])
                + bf2f(contrib[(size_t)sl2 * 1024 + c]);
          }
        }
      }
    }
  }
}

// ---------------- launch ----------------
extern "C" void kernel_launch(void* const* d_in, const int* in_sizes, int n_in,
                              void* d_out, int out_size, void* d_ws, size_t ws_size,
                              hipStream_t stream) {
  (void)in_sizes; (void)n_in; (void)out_size; (void)ws_size;
  const float* x      = (const float*)d_in[0];
  const float* Wg     = (const float*)d_in[1];
  const float* w_gate = (const float*)d_in[2];
  const float* w_up   = (const float*)d_in[3];
  const float* w_down = (const float*)d_in[4];
  const float* sg     = (const float*)d_in[5];
  const float* su     = (const float*)d_in[6];
  const float* sd     = (const float*)d_in[7];
  float* out = (float*)d_out;

  char* ws = (char*)d_ws;
  size_t o = 0;
  ushort_t* xb    = (ushort_t*)(ws + o); o += (size_t)TOK * DIM * 2;
  ushort_t* Wsh1  = (ushort_t*)(ws + o); o += (size_t)1024 * 1024 * 2;
  ushort_t* Wsd   = (ushort_t*)(ws + o); o += (size_t)1024 * 512 * 2;
  ushort_t* Wgu   = (ushort_t*)(ws + o); o += (size_t)NEXP * 512 * 1024 * 2;
  ushort_t* Wd    = (ushort_t*)(ws + o); o += (size_t)NEXP * 1024 * 256 * 2;
  ushort_t* hs    = (ushort_t*)(ws + o); o += (size_t)TOK * 512 * 2;
  ushort_t* he    = (ushort_t*)(ws + o); o += (size_t)TOK * TOPK * 256 * 2;
  int*   tid   = (int*)(ws + o);   o += (size_t)TOK * TOPK * 4;
  float* tw    = (float*)(ws + o); o += (size_t)TOK * TOPK * 4;
  int*   tok   = (int*)(ws + o);   o += (size_t)TOK * TOPK * 4;
  float* wgt   = (float*)(ws + o); o += (size_t)TOK * TOPK * 4;
  int*   slotof= (int*)(ws + o);   o += (size_t)TOK * TOPK * 4;
  int*   cnt   = (int*)(ws + o);   o += 64;
  int*   offp  = (int*)(ws + o);   o += 64;
  int*   cnt2  = (int*)(ws + o);   o += 64;
  ushort_t* contrib = (ushort_t*)(ws + o);  // TOK*TOPK*DIM bf16 (33.5 MB)

  k_router_cast<<<TOK / 4, 256, 0, stream>>>(x, Wg, xb, tid, tw);
  k_transpose_all<<<1280, 256, 0, stream>>>(sg, su, sd, w_gate, w_up, w_down,
                                            Wsh1, Wsd, Wgu, Wd);
  k_scan<<<1, 256, 0, stream>>>(tid, cnt, offp, cnt2);
  k_scatter<<<TOK / 256, 256, 0, stream>>>(tid, tw, offp, cnt2, tok, wgt, slotof);

  // merged GEMM1 (routed gathered + shared), 16*16*4 = 1024 blocks
  k_gemm1d<1024, 512, 0><<<1024, 256, 0, stream>>>(
      xb, Wgu, Wsh1, he, hs, nullptr, nullptr, tok, wgt, cnt, offp, nullptr);
  // routed GEMM2 -> bf16 contrib, 8*16*8 = 1024 blocks
  k_gemm1d<256, 1024, 1><<<1024, 256, 0, stream>>>(
      he, Wd, nullptr, nullptr, nullptr, contrib, nullptr, tok, wgt, cnt, offp,
      nullptr);
  // shared GEMM2 + combine -> out, 1*64*8 = 512 blocks
  k_gemm1d<512, 1024, 2><<<512, 256, 0, stream>>>(
      hs, Wsd, nullptr, nullptr, nullptr, contrib, out, tok, wgt, cnt, offp,
      slotof);
}